// Round 2
// baseline (101320.831 us; speedup 1.0000x reference)
//
#include <hip/hip_runtime.h>
#include <math.h>

#define T 16384

__device__ __forceinline__ float softplusf_(float x) {
    return (x > 15.f) ? x : __logf(1.f + __expf(x));
}
__device__ __forceinline__ float sigmoidf_(float x) {
    return 1.f / (1.f + __expf(-x));
}
__device__ __forceinline__ float tanh_fast(float x) {
    float xc = fminf(fmaxf(x, -15.f), 15.f);
    float e = __expf(2.f * xc);
    return (e - 1.f) / (e + 1.f);
}
// Barrier with LDS-only drain: does NOT wait vmcnt, so global prefetch loads
// and fire-and-forget trajectory stores stay in flight across steps.
__device__ __forceinline__ void bar_lds() {
    asm volatile("s_waitcnt lgkmcnt(0)\n\ts_barrier" ::: "memory");
}

// ---------------------------------------------------------------------------
// Precompute x-dependent matvec parts for all timesteps (fully parallel):
//   Aq[t,j] = x[t,:] @ W_q_y[0:128, j]
//   Ae[t,j] = x[t,:] @ W_enc[0:128, j]
//   Ah[t,o] = x[t,:] @ W_ih[65:193, o]
// ---------------------------------------------------------------------------
__global__ __launch_bounds__(256) void k_pre(
    const float* __restrict__ x,
    const float* __restrict__ Wqy, const float* __restrict__ Wenc,
    const float* __restrict__ Wih,
    float* __restrict__ Aq, float* __restrict__ Ae, float* __restrict__ Ah)
{
    __shared__ float xs[16 * 128];
    const int t0 = blockIdx.x * 16;
    for (int r = threadIdx.x; r < 16 * 128; r += 256) xs[r] = x[t0 * 128 + r];
    __syncthreads();
    const int j = threadIdx.x;
    for (int tt = 0; tt < 16; ++tt) {
        float aq = 0.f, ae = 0.f;
#pragma unroll 8
        for (int i = 0; i < 128; ++i) {
            float xv = xs[tt * 128 + i];
            aq = fmaf(xv, Wqy[i * 256 + j], aq);
            ae = fmaf(xv, Wenc[i * 256 + j], ae);
        }
        Aq[(size_t)(t0 + tt) * 256 + j] = aq;
        Ae[(size_t)(t0 + tt) * 256 + j] = ae;
    }
    if (j < 128) {
        for (int tt = 0; tt < 16; ++tt) {
            float ah = 0.f;
#pragma unroll 8
            for (int i = 0; i < 128; ++i)
                ah = fmaf(xs[tt * 128 + i], Wih[(65 + i) * 128 + j], ah);
            Ah[(size_t)(t0 + tt) * 128 + j] = ah;
        }
    }
}

// ---------------------------------------------------------------------------
// Sequential scan: 1 block, 512 threads, recurrent weights in registers.
// Produces trajectory: h_st[T,128], z_st[T,64], em_st/es_st[T,64], y_st[T].
// ---------------------------------------------------------------------------
__global__ __launch_bounds__(512, 1) void k_scan(
    const float* __restrict__ Wqy, const float* __restrict__ qpr,
    const float* __restrict__ Wenc,
    const float* __restrict__ Wem0, const float* __restrict__ Wes0,
    const float* __restrict__ Wih, const float* __restrict__ Whh,
    const float* __restrict__ yin_g, const float* __restrict__ eu_g,
    const float* __restrict__ ez_g,
    const float* __restrict__ Aq, const float* __restrict__ Ae,
    const float* __restrict__ Ah,
    float* __restrict__ h_st, float* __restrict__ z_st,
    float* __restrict__ em_st, float* __restrict__ es_st,
    float* __restrict__ y_st)
{
    const int tid = threadIdx.x;
    // S1/S3 mapping: 256 outputs x 2 chunks of 64 over h
    const int j  = tid >> 1, c1 = tid & 1;
    // S4 mapping: 64 m x {mean,std} x 4 chunks of 64 over eh
    const int m4 = tid >> 3; const int k4 = (tid >> 2) & 1; const int c4 = tid & 3;
    const int rot4 = c4 * 8;          // bank-conflict rotation for eh reads
    // S5 mapping: 128 outputs x 4 chunks (16 z + 32 h each)
    const int o5 = tid >> 2, c5 = tid & 3;
    const int rot5 = c5 * 8;          // bank-conflict rotation for h reads

    // --- load persistent weights into registers (static indexing) ---
    float wqh[64], weh[64], wms[64], wz5[16], wh5[32];
#pragma unroll
    for (int k = 0; k < 64; ++k) wqh[k] = Wqy[(128 + c1 * 64 + k) * 256 + j];
#pragma unroll
    for (int k = 0; k < 64; ++k) weh[k] = Wenc[(129 + c1 * 64 + k) * 256 + j];
    const float wey = Wenc[128 * 256 + j];
    const float qpj = qpr[j];
    const float* Wm = k4 ? Wes0 : Wem0;
#pragma unroll
    for (int k = 0; k < 64; ++k)      // pre-rotated to match swizzled eh reads
        wms[k] = Wm[(c4 * 64 + ((k + rot4) & 63)) * 64 + m4];
#pragma unroll
    for (int k = 0; k < 16; ++k) wz5[k] = Wih[(1 + c5 * 16 + k) * 128 + o5];
#pragma unroll
    for (int k = 0; k < 32; ++k)      // pre-rotated to match swizzled h reads
        wh5[k] = Whh[(c5 * 32 + ((k + rot5) & 31)) * 128 + o5];
    const float wihy = Wih[o5];

    __shared__ float h_lds[2][128];
    __shared__ float eh_lds[256];
    __shared__ float z_lds[64];
    __shared__ float red[8];
    if (tid < 128) { h_lds[0][tid] = 0.f; h_lds[1][tid] = 0.f; }
    __syncthreads();

    // prefetch t=0 stream values
    float aq_n = Aq[j];
    float ae_n = Ae[j];
    float yin_n = yin_g[0];
    float eu_n = eu_g[0];

    for (int t = 0; t < T; ++t) {
        const int cur = t & 1;
        const float aq = aq_n, ae = ae_n, yin = yin_n, eu = eu_n;
        const int tn = (t + 1 < T) ? t + 1 : t;
        aq_n = Aq[(size_t)tn * 256 + j];
        ae_n = Ae[(size_t)tn * 256 + j];
        yin_n = yin_g[tn];
        eu_n = eu_g[tn];
        const float ez = ez_g[(size_t)t * 64 + m4];
        const float ah = Ah[(size_t)t * 128 + o5];
        const float* __restrict__ hb = &h_lds[cur][c1 * 64];

        float y_t, ehdot;
        if (yin == -1.0f) {
            // unlabeled: fused q-dot + eh-dot sharing the h LDS reads
            float a0 = 0.f, a1 = 0.f, e0 = 0.f, e1 = 0.f;
#pragma unroll
            for (int k = 0; k < 64; k += 2) {
                float h0 = hb[k], h1 = hb[k + 1];
                a0 = fmaf(h0, wqh[k],     a0);
                a1 = fmaf(h1, wqh[k + 1], a1);
                e0 = fmaf(h0, weh[k],     e0);
                e1 = fmaf(h1, weh[k + 1], e1);
            }
            float s = a0 + a1;
            ehdot = e0 + e1;
            s += __shfl_xor(s, 1);
            ehdot += __shfl_xor(ehdot, 1);
            float qh = fmaxf(aq + s, 0.f);
            float cq = (c1 == 0) ? qh * qpj : 0.f;
#pragma unroll
            for (int d = 1; d < 64; d <<= 1) cq += __shfl_xor(cq, d);
            if ((tid & 63) == 0) red[tid >> 6] = cq;
            bar_lds();                                     // B1
            float qlog = ((red[0] + red[1]) + (red[2] + red[3])) +
                         ((red[4] + red[5]) + (red[6] + red[7]));
            y_t = sigmoidf_((__logf(eu) - __logf(1.f - eu)) + qlog);
        } else {
            // labeled: eh-dot only
            float e0 = 0.f, e1 = 0.f, e2 = 0.f, e3 = 0.f;
#pragma unroll
            for (int k = 0; k < 64; k += 4) {
                e0 = fmaf(hb[k],     weh[k],     e0);
                e1 = fmaf(hb[k + 1], weh[k + 1], e1);
                e2 = fmaf(hb[k + 2], weh[k + 2], e2);
                e3 = fmaf(hb[k + 3], weh[k + 3], e3);
            }
            ehdot = (e0 + e1) + (e2 + e3);
            ehdot += __shfl_xor(ehdot, 1);
            y_t = yin;
        }

        // S3: eh = relu(Ae + y*wey + h @ We_h)
        {
            float eh = fmaxf(fmaf(y_t, wey, ae) + ehdot, 0.f);
            if (c1 == 0) eh_lds[j] = eh;
        }
        bar_lds();                                         // B3

        // S5 h-part (independent of eh/z): hides eh ds_read latency
        float h5 = fmaf(y_t, wihy, ah);
        {
            const float* __restrict__ hb5 = &h_lds[cur][c5 * 32];
            float a0 = 0.f, a1 = 0.f, a2 = 0.f, a3 = 0.f;
#pragma unroll
            for (int k = 0; k < 32; k += 4) {
                const int idx = (k + rot5) & 31;
                a0 = fmaf(hb5[idx],     wh5[k],     a0);
                a1 = fmaf(hb5[idx + 1], wh5[k + 1], a1);
                a2 = fmaf(hb5[idx + 2], wh5[k + 2], a2);
                a3 = fmaf(hb5[idx + 3], wh5[k + 3], a3);
            }
            h5 += (a0 + a1) + (a2 + a3);
        }

        // S4: em/es = eh @ W_enc_mean/std ; z = ez*softplus(es)+em
        {
            const float* __restrict__ eb = &eh_lds[c4 * 64];
            float a0 = 0.f, a1 = 0.f, a2 = 0.f, a3 = 0.f;
#pragma unroll
            for (int k = 0; k < 64; k += 4) {
                const int idx = (k + rot4) & 63;
                a0 = fmaf(eb[idx],     wms[k],     a0);
                a1 = fmaf(eb[idx + 1], wms[k + 1], a1);
                a2 = fmaf(eb[idx + 2], wms[k + 2], a2);
                a3 = fmaf(eb[idx + 3], wms[k + 3], a3);
            }
            float s = (a0 + a1) + (a2 + a3);
            s += __shfl_xor(s, 1);
            s += __shfl_xor(s, 2);
            float other = __shfl_xor(s, 4);
            float em_pre = k4 ? other : s;
            float es_pre = k4 ? s : other;
            float es = softplusf_(es_pre);
            float zm = fmaf(ez, es, em_pre);
            if ((tid & 7) == 0) {
                z_lds[m4] = zm;
                z_st[(size_t)t * 64 + m4] = zm;
                em_st[(size_t)t * 64 + m4] = em_pre;
                es_st[(size_t)t * 64 + m4] = es;
            }
        }
        bar_lds();                                         // B4

        // S5: h_new = tanh(h5 + z @ Wih_z)
        {
            const float* __restrict__ zb = &z_lds[c5 * 16];
            float a0 = 0.f, a1 = 0.f, a2 = 0.f, a3 = 0.f;
#pragma unroll
            for (int k = 0; k < 16; k += 4) {
                a0 = fmaf(zb[k],     wz5[k],     a0);
                a1 = fmaf(zb[k + 1], wz5[k + 1], a1);
                a2 = fmaf(zb[k + 2], wz5[k + 2], a2);
                a3 = fmaf(zb[k + 3], wz5[k + 3], a3);
            }
            float s = (a0 + a1) + (a2 + a3);
            s += __shfl_xor(s, 1);
            s += __shfl_xor(s, 2);
            float hn = tanh_fast(h5 + s);
            if (c5 == 0) {
                h_lds[cur ^ 1][o5] = hn;
                h_st[(size_t)t * 128 + o5] = hn;
            }
            if (tid == 0) y_st[t] = y_t;
        }
        bar_lds();                                         // B5
    }
}

// ---------------------------------------------------------------------------
// Post-pass: one block per timestep; recompute everything off the critical
// path from the stored trajectory; write 7 per-step loss partials.
// ---------------------------------------------------------------------------
__global__ __launch_bounds__(256) void k_post(
    const float* __restrict__ x, const float* __restrict__ yin_g,
    const float* __restrict__ Wpz, const float* __restrict__ Wpzm,
    const float* __restrict__ Wpzs,
    const float* __restrict__ Wpy, const float* __restrict__ ppr,
    const float* __restrict__ Wqy, const float* __restrict__ qpr,
    const float* __restrict__ Wd, const float* __restrict__ Wdm,
    const float* __restrict__ Wds,
    const float* __restrict__ Aq,
    const float* __restrict__ h_st, const float* __restrict__ z_st,
    const float* __restrict__ em_st, const float* __restrict__ es_st,
    const float* __restrict__ y_st,
    float* __restrict__ part)
{
    const float CC = -0.9189385332046727f;  // -0.5*log(2*pi)
    const int t = blockIdx.x;
    const int tid = threadIdx.x;
    __shared__ float xp[128], xdv[128], xcv[128], hp[128];
    __shared__ float zp[64], ztv[64], emv[64], esv[64];
    __shared__ float pzh[256], dhv[256];
    __shared__ float pmv[64], psv[64], dmv[128], dsv[128];
    __shared__ float rl[16];

    const int tp = t ? (t - 1) : (T - 1);
    if (tid < 128) {
        xp[tid]  = x[(size_t)tp * 128 + tid];
        xdv[tid] = t ? x[(size_t)(t - 1) * 128 + tid] : 0.f;   // decoder carry init = 0
        xcv[tid] = x[(size_t)t * 128 + tid];
        hp[tid]  = t ? h_st[(size_t)(t - 1) * 128 + tid] : 0.f;
    } else {
        int m = tid - 128;
        if (m < 64) {
            zp[m]  = t ? z_st[(size_t)(t - 1) * 64 + m] : 0.f;
            ztv[m] = z_st[(size_t)t * 64 + m];
        } else {
            m -= 64;
            emv[m] = em_st[(size_t)t * 64 + m];
            esv[m] = es_st[(size_t)t * 64 + m];
        }
    }
    __syncthreads();

    const float y_t = y_st[t];
    const float y_prev = t ? y_st[t - 1] : 0.f;
    const float lf = (yin_g[t] != -1.0f) ? 1.f : 0.f;
    const int jj = tid;

    // p(y) logit contribution
    float ap = 0.f;
#pragma unroll 4
    for (int i = 0; i < 128; ++i) ap = fmaf(xp[i], Wpy[i * 256 + jj], ap);
    ap = fmaf(y_prev, Wpy[128 * 256 + jj], ap);
    float cp = fmaxf(ap, 0.f) * ppr[jj];

    // q(y) logit contribution
    float aqv = Aq[(size_t)t * 256 + jj];
#pragma unroll 4
    for (int i = 0; i < 128; ++i) aqv = fmaf(hp[i], Wqy[(128 + i) * 256 + jj], aqv);
    float cq = fmaxf(aqv, 0.f) * qpr[jj];

    // prior z hidden
    float az = 0.f;
#pragma unroll 4
    for (int m = 0; m < 64; ++m) az = fmaf(zp[m], Wpz[m * 256 + jj], az);
    pzh[jj] = fmaxf(az, 0.f);

    // decoder hidden
    float ad = 0.f;
#pragma unroll 4
    for (int i = 0; i < 128; ++i) ad = fmaf(xdv[i], Wd[i * 256 + jj], ad);
#pragma unroll 4
    for (int m = 0; m < 64; ++m) ad = fmaf(ztv[m], Wd[(128 + m) * 256 + jj], ad);
    ad = fmaf(y_t, Wd[192 * 256 + jj], ad);
    dhv[jj] = fmaxf(ad, 0.f);
    __syncthreads();

    // dm/ds: 256 threads (128 dims x {mean,std})
    {
        const int i_ = tid & 127;
        const float* W = (tid < 128) ? Wdm : Wds;
        float a = 0.f;
#pragma unroll 4
        for (int q2 = 0; q2 < 256; ++q2) a = fmaf(dhv[q2], W[q2 * 128 + i_], a);
        if (tid < 128) dmv[i_] = a; else dsv[i_] = softplusf_(a);
    }
    // pm/ps: 128 threads (64 dims x {mean,std})
    if (tid < 128) {
        const int m = tid & 63;
        const float* W = (tid < 64) ? Wpzm : Wpzs;
        float a = 0.f;
#pragma unroll 4
        for (int q2 = 0; q2 < 256; ++q2) a = fmaf(pzh[q2], W[q2 * 64 + m], a);
        if (tid < 64) pmv[m] = a; else psv[m] = softplusf_(a);
    }
    __syncthreads();

    float kldc = 0.f, recc = 0.f;
    if (tid < 64) {
        float es = esv[tid], em = emv[tid], pm = pmv[tid], ps = psv[tid];
        float d = em - pm;
        kldc = __logf(ps / es) + (es * es + d * d) / (2.f * ps * ps) - 0.5f;
    }
    if (tid < 128) {
        float dm = dmv[tid], ds = dsv[tid], xv = xcv[tid];
        float d = xv - dm;
        recc = CC + __logf(ds) + d * d / (2.f * ds * ds);
    }

    // block-reduce 4 values
#pragma unroll
    for (int d = 1; d < 64; d <<= 1) {
        cp += __shfl_xor(cp, d);
        cq += __shfl_xor(cq, d);
        kldc += __shfl_xor(kldc, d);
        recc += __shfl_xor(recc, d);
    }
    if ((tid & 63) == 0) {
        const int w = tid >> 6;
        rl[w * 4 + 0] = cp; rl[w * 4 + 1] = cq;
        rl[w * 4 + 2] = kldc; rl[w * 4 + 3] = recc;
    }
    __syncthreads();
    if (tid == 0) {
        float plog = rl[0] + rl[4] + rl[8]  + rl[12];
        float qlog = rl[1] + rl[5] + rl[9]  + rl[13];
        float kld  = rl[2] + rl[6] + rl[10] + rl[14];
        float rec  = rl[3] + rl[7] + rl[11] + rl[15];
        float p = sigmoidf_(plog), q = sigmoidf_(qlog);
        float bce  = -(y_t * __logf(p) + (1.f - y_t) * __logf(1.f - p));
        float addt = y_t * __logf(p * q) + (1.f - y_t) * __logf((1.f - p) * (1.f - q));
        float kcat = p * __logf(p / q) + (1.f - p) * __logf((1.f - p) / (1.f - q));
        float ul = 1.f - lf;
        float* pr = part + (size_t)t * 7;
        pr[0] = lf * kld;  pr[1] = lf * rec;  pr[2] = lf * bce;
        pr[3] = ul * kld;  pr[4] = ul * rec;  pr[5] = ul * kcat;
        pr[6] = lf * addt;
    }
}

// ---------------------------------------------------------------------------
// Deterministic final reduction of the per-step partials (7 outputs).
// ---------------------------------------------------------------------------
__global__ __launch_bounds__(256) void k_final(const float* __restrict__ part,
                                               float* __restrict__ out)
{
    const int o = blockIdx.x;
    float s = 0.f;
    for (int b = threadIdx.x; b < T; b += 256) s += part[(size_t)b * 7 + o];
#pragma unroll
    for (int d = 1; d < 64; d <<= 1) s += __shfl_xor(s, d);
    __shared__ float l[4];
    if ((threadIdx.x & 63) == 0) l[threadIdx.x >> 6] = s;
    __syncthreads();
    if (threadIdx.x == 0) out[o] = (l[0] + l[1]) + (l[2] + l[3]);
}

extern "C" void kernel_launch(void* const* d_in, const int* in_sizes, int n_in,
                              void* d_out, int out_size, void* d_ws, size_t ws_size,
                              hipStream_t stream) {
    (void)in_sizes; (void)n_in; (void)out_size; (void)ws_size;
    const float* x    = (const float*)d_in[0];
    const float* yin  = (const float*)d_in[1];
    const float* ez   = (const float*)d_in[2];
    const float* eu   = (const float*)d_in[3];
    const float* Wpz  = (const float*)d_in[4];
    const float* Wpzm = (const float*)d_in[5];
    const float* Wpzs = (const float*)d_in[6];
    const float* Wpy  = (const float*)d_in[7];
    const float* ppr  = (const float*)d_in[8];
    const float* Wqy  = (const float*)d_in[9];
    const float* qpr  = (const float*)d_in[10];
    const float* Wenc = (const float*)d_in[11];
    const float* Wem  = (const float*)d_in[12];
    const float* Wes  = (const float*)d_in[13];
    const float* Wd   = (const float*)d_in[14];
    const float* Wdm  = (const float*)d_in[15];
    const float* Wds  = (const float*)d_in[16];
    const float* Wih  = (const float*)d_in[17];
    const float* Whh  = (const float*)d_in[18];

    float* ws = (float*)d_ws;
    float* Aq    = ws;                           // T*256
    float* Ae    = Aq    + (size_t)T * 256;      // T*256
    float* Ah    = Ae    + (size_t)T * 256;      // T*128
    float* h_st  = Ah    + (size_t)T * 128;      // T*128
    float* z_st  = h_st  + (size_t)T * 128;      // T*64
    float* em_st = z_st  + (size_t)T * 64;       // T*64
    float* es_st = em_st + (size_t)T * 64;       // T*64
    float* y_st  = es_st + (size_t)T * 64;       // T
    float* part  = y_st  + (size_t)T;            // T*7

    k_pre<<<T / 16, 256, 0, stream>>>(x, Wqy, Wenc, Wih, Aq, Ae, Ah);
    k_scan<<<1, 512, 0, stream>>>(Wqy, qpr, Wenc, Wem, Wes, Wih, Whh,
                                  yin, eu, ez, Aq, Ae, Ah,
                                  h_st, z_st, em_st, es_st, y_st);
    k_post<<<T, 256, 0, stream>>>(x, yin, Wpz, Wpzm, Wpzs, Wpy, ppr, Wqy, qpr,
                                  Wd, Wdm, Wds, Aq, h_st, z_st, em_st, es_st,
                                  y_st, part);
    k_final<<<7, 256, 0, stream>>>(part, (float*)d_out);
}

// Round 3
// 39821.603 us; speedup vs baseline: 2.5444x; 2.5444x over previous
//
#include <hip/hip_runtime.h>
#include <math.h>

#define T 16384

typedef float f32x4  __attribute__((ext_vector_type(4)));
typedef float f32x16 __attribute__((ext_vector_type(16)));

__device__ __forceinline__ float softplusf_(float x) {
    return (x > 15.f) ? x : __logf(1.f + __expf(x));
}
__device__ __forceinline__ float sigmoidf_(float x) {
    return 1.f / (1.f + __expf(-x));
}
__device__ __forceinline__ float tanh_fast(float x) {
    float xc = fminf(fmaxf(x, -15.f), 15.f);
    float e = __expf(2.f * xc);
    return (e - 1.f) / (e + 1.f);
}

// 16-wide dot-step, 4 accumulators, acc i takes lanes k%4==i (matches round-1
// "for k+=4 {a0:k, a1:k+1, a2:k+2, a3:k+3}" summation order exactly).
#define D16(A0,A1,A2,A3,HB,OFF,W) do{ \
  A0=fmaf((HB)[(OFF)+0],(W)[0],A0);  A1=fmaf((HB)[(OFF)+1],(W)[1],A1); \
  A2=fmaf((HB)[(OFF)+2],(W)[2],A2);  A3=fmaf((HB)[(OFF)+3],(W)[3],A3); \
  A0=fmaf((HB)[(OFF)+4],(W)[4],A0);  A1=fmaf((HB)[(OFF)+5],(W)[5],A1); \
  A2=fmaf((HB)[(OFF)+6],(W)[6],A2);  A3=fmaf((HB)[(OFF)+7],(W)[7],A3); \
  A0=fmaf((HB)[(OFF)+8],(W)[8],A0);  A1=fmaf((HB)[(OFF)+9],(W)[9],A1); \
  A2=fmaf((HB)[(OFF)+10],(W)[10],A2); A3=fmaf((HB)[(OFF)+11],(W)[11],A3); \
  A0=fmaf((HB)[(OFF)+12],(W)[12],A0); A1=fmaf((HB)[(OFF)+13],(W)[13],A3*0.f+fmaf((HB)[(OFF)+13],(W)[13],0.f)+A1-A1+A1); \
}while(0)
// NOTE: macro above intentionally unused (kept simple version below)
#undef D16
#define D16(A0,A1,A2,A3,HB,OFF,W) do{ \
  A0=fmaf((HB)[(OFF)+0],(W)[0],A0);  A1=fmaf((HB)[(OFF)+1],(W)[1],A1); \
  A2=fmaf((HB)[(OFF)+2],(W)[2],A2);  A3=fmaf((HB)[(OFF)+3],(W)[3],A3); \
  A0=fmaf((HB)[(OFF)+4],(W)[4],A0);  A1=fmaf((HB)[(OFF)+5],(W)[5],A1); \
  A2=fmaf((HB)[(OFF)+6],(W)[6],A2);  A3=fmaf((HB)[(OFF)+7],(W)[7],A3); \
  A0=fmaf((HB)[(OFF)+8],(W)[8],A0);  A1=fmaf((HB)[(OFF)+9],(W)[9],A1); \
  A2=fmaf((HB)[(OFF)+10],(W)[10],A2); A3=fmaf((HB)[(OFF)+11],(W)[11],A3); \
  A0=fmaf((HB)[(OFF)+12],(W)[12],A0); A1=fmaf((HB)[(OFF)+13],(W)[13],A1); \
  A2=fmaf((HB)[(OFF)+14],(W)[14],A2); A3=fmaf((HB)[(OFF)+15],(W)[15],A3); \
}while(0)

#define SET16(V,G,B) do{ \
  V[0]=G((B)+0);  V[1]=G((B)+1);  V[2]=G((B)+2);  V[3]=G((B)+3); \
  V[4]=G((B)+4);  V[5]=G((B)+5);  V[6]=G((B)+6);  V[7]=G((B)+7); \
  V[8]=G((B)+8);  V[9]=G((B)+9);  V[10]=G((B)+10); V[11]=G((B)+11); \
  V[12]=G((B)+12); V[13]=G((B)+13); V[14]=G((B)+14); V[15]=G((B)+15); \
}while(0)

// ---------------------------------------------------------------------------
// Precompute x-dependent matvec parts (fully parallel).
// ---------------------------------------------------------------------------
__global__ __launch_bounds__(256) void k_pre(
    const float* __restrict__ x,
    const float* __restrict__ Wqy, const float* __restrict__ Wenc,
    const float* __restrict__ Wih,
    float* __restrict__ Aq, float* __restrict__ Ae, float* __restrict__ Ah)
{
    __shared__ float xs[16 * 128];
    const int t0 = blockIdx.x * 16;
    for (int r = threadIdx.x; r < 16 * 128; r += 256) xs[r] = x[t0 * 128 + r];
    __syncthreads();
    const int j = threadIdx.x;
    for (int tt = 0; tt < 16; ++tt) {
        float aq = 0.f, ae = 0.f;
#pragma unroll 8
        for (int i = 0; i < 128; ++i) {
            float xv = xs[tt * 128 + i];
            aq = fmaf(xv, Wqy[i * 256 + j], aq);
            ae = fmaf(xv, Wenc[i * 256 + j], ae);
        }
        Aq[(size_t)(t0 + tt) * 256 + j] = aq;
        Ae[(size_t)(t0 + tt) * 256 + j] = ae;
    }
    if (j < 128) {
        for (int tt = 0; tt < 16; ++tt) {
            float ah = 0.f;
#pragma unroll 8
            for (int i = 0; i < 128; ++i)
                ah = fmaf(xs[tt * 128 + i], Wih[(65 + i) * 128 + j], ah);
            Ah[(size_t)(t0 + tt) * 128 + j] = ah;
        }
    }
}

// ---------------------------------------------------------------------------
// Sequential scan. 1 block, 512 threads. Weights: 176 f/thread in named
// ext-vector registers; W_q_y h-part in LDS (thread-major float4, conflict-
// free); streams batch-staged (B=4) in LDS; trajectory batch-flushed.
// ---------------------------------------------------------------------------
__global__ __launch_bounds__(512, 2) void k_scan(
    const float* __restrict__ Wqy, const float* __restrict__ qpr,
    const float* __restrict__ Wenc,
    const float* __restrict__ Wem0, const float* __restrict__ Wes0,
    const float* __restrict__ Wih, const float* __restrict__ Whh,
    const float* __restrict__ yin_g, const float* __restrict__ eu_g,
    const float* __restrict__ ez_g,
    const float* __restrict__ Aq, const float* __restrict__ Ae,
    const float* __restrict__ Ah,
    float* __restrict__ h_st, float* __restrict__ z_st,
    float* __restrict__ em_st, float* __restrict__ es_st,
    float* __restrict__ y_st)
{
    const int tid = threadIdx.x;
    const int j   = tid >> 1, c1 = tid & 1;              // S1/S3 mapping
    const int m4  = tid >> 3; const int k4s = (tid >> 2) & 1; const int c4 = tid & 3; // S4
    const int o5  = tid >> 2, c5 = tid & 3;              // S5

    // ---- LDS (total ~153.5 KB of 160 KB) ----
    __shared__ __align__(16) f32x4 wq4[16][512];         // 128 KB: W_q_y h-part
    __shared__ __align__(16) float s_aq[4][256];
    __shared__ __align__(16) float s_ae[4][256];
    __shared__ __align__(16) float s_ah[4][128];
    __shared__ __align__(16) float s_ez[4][64];
    __shared__ __align__(16) float s_yin[4];
    __shared__ __align__(16) float s_eu[4];
    __shared__ __align__(16) float t_h[4][128];
    __shared__ __align__(16) float t_z[4][64];
    __shared__ __align__(16) float t_em[4][64];
    __shared__ __align__(16) float t_es[4][64];
    __shared__ float t_y[4];
    __shared__ __align__(16) float h_lds[2][128];
    __shared__ __align__(16) float h5c[2][4][132];       // padded replicas (banks 4*c5+k)
    __shared__ __align__(16) float eh4[4][260];          // padded replicas (banks 4*c4+k)
    __shared__ __align__(16) float z_lds[64];
    __shared__ float red[8];

    // ---- persistent weights in named vector registers (constant indices) ----
    f32x16 weh0, weh1, weh2, weh3, wms0, wms1, wms2, wms3, wh5a, wh5b, wz5v;
    {
        auto ge = [&](int k) { return Wenc[(129 + c1 * 64 + k) * 256 + j]; };
        SET16(weh0, ge, 0); SET16(weh1, ge, 16); SET16(weh2, ge, 32); SET16(weh3, ge, 48);
    }
    const float wey = Wenc[128 * 256 + j];
    const float qpj = qpr[j];
    {
        const float* Wm = k4s ? Wes0 : Wem0;
        auto gm = [&](int k) { return Wm[(c4 * 64 + k) * 64 + m4]; };
        SET16(wms0, gm, 0); SET16(wms1, gm, 16); SET16(wms2, gm, 32); SET16(wms3, gm, 48);
    }
    {
        auto gh = [&](int k) { return Whh[(c5 * 32 + k) * 128 + o5]; };
        SET16(wh5a, gh, 0); SET16(wh5b, gh, 16);
    }
    {
        auto gz = [&](int k) { return Wih[(1 + c5 * 16 + k) * 128 + o5]; };
        SET16(wz5v, gz, 0);
    }
    const float wihy = Wih[o5];

    // W_q_y h-part -> LDS, thread-major float4 (lane-consecutive => no conflicts)
    for (int kq = 0; kq < 16; ++kq) {
        f32x4 v;
        v[0] = Wqy[(128 + c1 * 64 + 4 * kq + 0) * 256 + j];
        v[1] = Wqy[(128 + c1 * 64 + 4 * kq + 1) * 256 + j];
        v[2] = Wqy[(128 + c1 * 64 + 4 * kq + 2) * 256 + j];
        v[3] = Wqy[(128 + c1 * 64 + 4 * kq + 3) * 256 + j];
        wq4[kq][tid] = v;
    }
    if (tid < 128) {
        h_lds[0][tid] = 0.f; h_lds[1][tid] = 0.f;
        h5c[0][0][tid] = 0.f; h5c[0][1][tid] = 0.f;
        h5c[0][2][tid] = 0.f; h5c[0][3][tid] = 0.f;
    }

    auto stage = [&](int t0) {
        if (tid < 256) {
            ((f32x4*)&s_aq[0][0])[tid] = ((const f32x4*)(Aq + (size_t)t0 * 256))[tid];
        } else {
            ((f32x4*)&s_ae[0][0])[tid - 256] = ((const f32x4*)(Ae + (size_t)t0 * 256))[tid - 256];
        }
        if (tid < 128) {
            ((f32x4*)&s_ah[0][0])[tid] = ((const f32x4*)(Ah + (size_t)t0 * 128))[tid];
        } else if (tid < 192) {
            ((f32x4*)&s_ez[0][0])[tid - 128] = ((const f32x4*)(ez_g + (size_t)t0 * 64))[tid - 128];
        } else if (tid == 192) {
            *(f32x4*)s_yin = *(const f32x4*)(yin_g + t0);
        } else if (tid == 193) {
            *(f32x4*)s_eu = *(const f32x4*)(eu_g + t0);
        }
    };
    auto flushb = [&](int t0) {
        if (tid < 128) {
            ((f32x4*)(h_st + (size_t)t0 * 128))[tid] = ((const f32x4*)&t_h[0][0])[tid];
        } else if (tid < 192) {
            ((f32x4*)(z_st + (size_t)t0 * 64))[tid - 128] = ((const f32x4*)&t_z[0][0])[tid - 128];
        } else if (tid < 256) {
            ((f32x4*)(em_st + (size_t)t0 * 64))[tid - 192] = ((const f32x4*)&t_em[0][0])[tid - 192];
        } else if (tid < 320) {
            ((f32x4*)(es_st + (size_t)t0 * 64))[tid - 256] = ((const f32x4*)&t_es[0][0])[tid - 256];
        } else if (tid < 324) {
            y_st[t0 + (tid - 320)] = t_y[tid - 320];
        }
    };

    for (int t0 = 0; t0 < T; t0 += 4) {
        if (t0) flushb(t0 - 4);
        stage(t0);
        __syncthreads();                                   // batch barrier

        for (int tt = 0; tt < 4; ++tt) {
            const int t = t0 + tt;
            const int cur = t & 1, nxt = cur ^ 1;
            const float aq  = s_aq[tt][j];
            const float ae  = s_ae[tt][j];
            const float yin = s_yin[tt];
            const float eu  = s_eu[tt];
            const float ez  = s_ez[tt][m4];
            const float ah  = s_ah[tt][o5];
            const float* __restrict__ hb = &h_lds[cur][c1 * 64];

            float y_t;
            if (yin == -1.0f) {   // unlabeled (wave-uniform branch)
                float a0 = 0.f, a1 = 0.f, a2 = 0.f, a3 = 0.f;
#pragma unroll
                for (int kq = 0; kq < 16; ++kq) {
                    f32x4 w = wq4[kq][tid];
                    a0 = fmaf(hb[4 * kq + 0], w[0], a0);
                    a1 = fmaf(hb[4 * kq + 1], w[1], a1);
                    a2 = fmaf(hb[4 * kq + 2], w[2], a2);
                    a3 = fmaf(hb[4 * kq + 3], w[3], a3);
                }
                float s = (a0 + a1) + (a2 + a3);
                s += __shfl_xor(s, 1);
                float qh = fmaxf(aq + s, 0.f);
                float cq = (c1 == 0) ? qh * qpj : 0.f;
#pragma unroll
                for (int d = 1; d < 64; d <<= 1) cq += __shfl_xor(cq, d);
                if ((tid & 63) == 0) red[tid >> 6] = cq;
                __syncthreads();                           // B1
                float qlog = ((red[0] + red[1]) + (red[2] + red[3])) +
                             ((red[4] + red[5]) + (red[6] + red[7]));
                y_t = sigmoidf_((__logf(eu) - __logf(1.f - eu)) + qlog);
            } else {
                y_t = yin;
            }

            // S3: eh = relu(Ae + y*wey + h @ We_h)
            {
                float e0 = 0.f, e1 = 0.f, e2 = 0.f, e3 = 0.f;
                D16(e0, e1, e2, e3, hb, 0,  weh0);
                D16(e0, e1, e2, e3, hb, 16, weh1);
                D16(e0, e1, e2, e3, hb, 32, weh2);
                D16(e0, e1, e2, e3, hb, 48, weh3);
                float ehs = (e0 + e1) + (e2 + e3);
                ehs += __shfl_xor(ehs, 1);
                float eh = fmaxf(fmaf(y_t, wey, ae) + ehs, 0.f);
                if (c1 == 0) {
                    eh4[0][j] = eh; eh4[1][j] = eh; eh4[2][j] = eh; eh4[3][j] = eh;
                }
            }
            __syncthreads();                               // B3

            // S4: em/es = eh @ W_enc_mean/std ; z = ez*softplus(es)+em
            {
                const float* __restrict__ eb = &eh4[c4][c4 * 64];
                float b0 = 0.f, b1 = 0.f, b2 = 0.f, b3 = 0.f;
                D16(b0, b1, b2, b3, eb, 0,  wms0);
                D16(b0, b1, b2, b3, eb, 16, wms1);
                D16(b0, b1, b2, b3, eb, 32, wms2);
                D16(b0, b1, b2, b3, eb, 48, wms3);
                float s = (b0 + b1) + (b2 + b3);
                s += __shfl_xor(s, 1);
                s += __shfl_xor(s, 2);
                float other = __shfl_xor(s, 4);
                float em_pre = k4s ? other : s;
                float es_pre = k4s ? s : other;
                float es = softplusf_(es_pre);
                float zm = fmaf(ez, es, em_pre);
                if ((tid & 7) == 0) {
                    z_lds[m4] = zm;
                    t_z[tt][m4] = zm; t_em[tt][m4] = em_pre; t_es[tt][m4] = es;
                }
            }
            __syncthreads();                               // B4

            // S5: h_new = tanh(Ah + y*wihy + z @ Wih_z + h @ W_hh)
            {
                const float* __restrict__ zb  = &z_lds[c5 * 16];
                const float* __restrict__ hb5 = &h5c[cur][c5][c5 * 32];
                float g0 = 0.f, g1 = 0.f, g2 = 0.f, g3 = 0.f;
                D16(g0, g1, g2, g3, zb, 0, wz5v);
                D16(g0, g1, g2, g3, hb5, 0,  wh5a);
                D16(g0, g1, g2, g3, hb5, 16, wh5b);
                float s = (g0 + g1) + (g2 + g3);
                s += __shfl_xor(s, 1);
                s += __shfl_xor(s, 2);
                float hn = tanh_fast(fmaf(y_t, wihy, ah) + s);
                if (c5 == 0) {
                    h_lds[nxt][o5] = hn;
                    h5c[nxt][0][o5] = hn; h5c[nxt][1][o5] = hn;
                    h5c[nxt][2][o5] = hn; h5c[nxt][3][o5] = hn;
                    t_h[tt][o5] = hn;
                }
                if (tid == 0) t_y[tt] = y_t;
            }
            __syncthreads();                               // B5
        }
    }
    flushb(T - 4);
}

// ---------------------------------------------------------------------------
// Post-pass: one block per timestep (unchanged from round 1).
// ---------------------------------------------------------------------------
__global__ __launch_bounds__(256) void k_post(
    const float* __restrict__ x, const float* __restrict__ yin_g,
    const float* __restrict__ Wpz, const float* __restrict__ Wpzm,
    const float* __restrict__ Wpzs,
    const float* __restrict__ Wpy, const float* __restrict__ ppr,
    const float* __restrict__ Wqy, const float* __restrict__ qpr,
    const float* __restrict__ Wd, const float* __restrict__ Wdm,
    const float* __restrict__ Wds,
    const float* __restrict__ Aq,
    const float* __restrict__ h_st, const float* __restrict__ z_st,
    const float* __restrict__ em_st, const float* __restrict__ es_st,
    const float* __restrict__ y_st,
    float* __restrict__ part)
{
    const float CC = -0.9189385332046727f;  // -0.5*log(2*pi)
    const int t = blockIdx.x;
    const int tid = threadIdx.x;
    __shared__ float xp[128], xdv[128], xcv[128], hp[128];
    __shared__ float zp[64], ztv[64], emv[64], esv[64];
    __shared__ float pzh[256], dhv[256];
    __shared__ float pmv[64], psv[64], dmv[128], dsv[128];
    __shared__ float rl[16];

    const int tp = t ? (t - 1) : (T - 1);
    if (tid < 128) {
        xp[tid]  = x[(size_t)tp * 128 + tid];
        xdv[tid] = t ? x[(size_t)(t - 1) * 128 + tid] : 0.f;
        xcv[tid] = x[(size_t)t * 128 + tid];
        hp[tid]  = t ? h_st[(size_t)(t - 1) * 128 + tid] : 0.f;
    } else {
        int m = tid - 128;
        if (m < 64) {
            zp[m]  = t ? z_st[(size_t)(t - 1) * 64 + m] : 0.f;
            ztv[m] = z_st[(size_t)t * 64 + m];
        } else {
            m -= 64;
            emv[m] = em_st[(size_t)t * 64 + m];
            esv[m] = es_st[(size_t)t * 64 + m];
        }
    }
    __syncthreads();

    const float y_t = y_st[t];
    const float y_prev = t ? y_st[t - 1] : 0.f;
    const float lf = (yin_g[t] != -1.0f) ? 1.f : 0.f;
    const int jj = tid;

    float ap = 0.f;
#pragma unroll 4
    for (int i = 0; i < 128; ++i) ap = fmaf(xp[i], Wpy[i * 256 + jj], ap);
    ap = fmaf(y_prev, Wpy[128 * 256 + jj], ap);
    float cp = fmaxf(ap, 0.f) * ppr[jj];

    float aqv = Aq[(size_t)t * 256 + jj];
#pragma unroll 4
    for (int i = 0; i < 128; ++i) aqv = fmaf(hp[i], Wqy[(128 + i) * 256 + jj], aqv);
    float cq = fmaxf(aqv, 0.f) * qpr[jj];

    float az = 0.f;
#pragma unroll 4
    for (int m = 0; m < 64; ++m) az = fmaf(zp[m], Wpz[m * 256 + jj], az);
    pzh[jj] = fmaxf(az, 0.f);

    float ad = 0.f;
#pragma unroll 4
    for (int i = 0; i < 128; ++i) ad = fmaf(xdv[i], Wd[i * 256 + jj], ad);
#pragma unroll 4
    for (int m = 0; m < 64; ++m) ad = fmaf(ztv[m], Wd[(128 + m) * 256 + jj], ad);
    ad = fmaf(y_t, Wd[192 * 256 + jj], ad);
    dhv[jj] = fmaxf(ad, 0.f);
    __syncthreads();

    {
        const int i_ = tid & 127;
        const float* W = (tid < 128) ? Wdm : Wds;
        float a = 0.f;
#pragma unroll 4
        for (int q2 = 0; q2 < 256; ++q2) a = fmaf(dhv[q2], W[q2 * 128 + i_], a);
        if (tid < 128) dmv[i_] = a; else dsv[i_] = softplusf_(a);
    }
    if (tid < 128) {
        const int m = tid & 63;
        const float* W = (tid < 64) ? Wpzm : Wpzs;
        float a = 0.f;
#pragma unroll 4
        for (int q2 = 0; q2 < 256; ++q2) a = fmaf(pzh[q2], W[q2 * 64 + m], a);
        if (tid < 64) pmv[m] = a; else psv[m] = softplusf_(a);
    }
    __syncthreads();

    float kldc = 0.f, recc = 0.f;
    if (tid < 64) {
        float es = esv[tid], em = emv[tid], pm = pmv[tid], ps = psv[tid];
        float d = em - pm;
        kldc = __logf(ps / es) + (es * es + d * d) / (2.f * ps * ps) - 0.5f;
    }
    if (tid < 128) {
        float dm = dmv[tid], ds = dsv[tid], xv = xcv[tid];
        float d = xv - dm;
        recc = CC + __logf(ds) + d * d / (2.f * ds * ds);
    }

#pragma unroll
    for (int d = 1; d < 64; d <<= 1) {
        cp += __shfl_xor(cp, d);
        cq += __shfl_xor(cq, d);
        kldc += __shfl_xor(kldc, d);
        recc += __shfl_xor(recc, d);
    }
    if ((tid & 63) == 0) {
        const int w = tid >> 6;
        rl[w * 4 + 0] = cp; rl[w * 4 + 1] = cq;
        rl[w * 4 + 2] = kldc; rl[w * 4 + 3] = recc;
    }
    __syncthreads();
    if (tid == 0) {
        float plog = rl[0] + rl[4] + rl[8]  + rl[12];
        float qlog = rl[1] + rl[5] + rl[9]  + rl[13];
        float kld  = rl[2] + rl[6] + rl[10] + rl[14];
        float rec  = rl[3] + rl[7] + rl[11] + rl[15];
        float p = sigmoidf_(plog), q = sigmoidf_(qlog);
        float bce  = -(y_t * __logf(p) + (1.f - y_t) * __logf(1.f - p));
        float addt = y_t * __logf(p * q) + (1.f - y_t) * __logf((1.f - p) * (1.f - q));
        float kcat = p * __logf(p / q) + (1.f - p) * __logf((1.f - p) / (1.f - q));
        float ul = 1.f - lf;
        float* pr = part + (size_t)t * 7;
        pr[0] = lf * kld;  pr[1] = lf * rec;  pr[2] = lf * bce;
        pr[3] = ul * kld;  pr[4] = ul * rec;  pr[5] = ul * kcat;
        pr[6] = lf * addt;
    }
}

__global__ __launch_bounds__(256) void k_final(const float* __restrict__ part,
                                               float* __restrict__ out)
{
    const int o = blockIdx.x;
    float s = 0.f;
    for (int b = threadIdx.x; b < T; b += 256) s += part[(size_t)b * 7 + o];
#pragma unroll
    for (int d = 1; d < 64; d <<= 1) s += __shfl_xor(s, d);
    __shared__ float l[4];
    if ((threadIdx.x & 63) == 0) l[threadIdx.x >> 6] = s;
    __syncthreads();
    if (threadIdx.x == 0) out[o] = (l[0] + l[1]) + (l[2] + l[3]);
}

extern "C" void kernel_launch(void* const* d_in, const int* in_sizes, int n_in,
                              void* d_out, int out_size, void* d_ws, size_t ws_size,
                              hipStream_t stream) {
    (void)in_sizes; (void)n_in; (void)out_size; (void)ws_size;
    const float* x    = (const float*)d_in[0];
    const float* yin  = (const float*)d_in[1];
    const float* ez   = (const float*)d_in[2];
    const float* eu   = (const float*)d_in[3];
    const float* Wpz  = (const float*)d_in[4];
    const float* Wpzm = (const float*)d_in[5];
    const float* Wpzs = (const float*)d_in[6];
    const float* Wpy  = (const float*)d_in[7];
    const float* ppr  = (const float*)d_in[8];
    const float* Wqy  = (const float*)d_in[9];
    const float* qpr  = (const float*)d_in[10];
    const float* Wenc = (const float*)d_in[11];
    const float* Wem  = (const float*)d_in[12];
    const float* Wes  = (const float*)d_in[13];
    const float* Wd   = (const float*)d_in[14];
    const float* Wdm  = (const float*)d_in[15];
    const float* Wds  = (const float*)d_in[16];
    const float* Wih  = (const float*)d_in[17];
    const float* Whh  = (const float*)d_in[18];

    float* ws = (float*)d_ws;
    float* Aq    = ws;                           // T*256
    float* Ae    = Aq    + (size_t)T * 256;      // T*256
    float* Ah    = Ae    + (size_t)T * 256;      // T*128
    float* h_st  = Ah    + (size_t)T * 128;      // T*128
    float* z_st  = h_st  + (size_t)T * 128;      // T*64
    float* em_st = z_st  + (size_t)T * 64;       // T*64
    float* es_st = em_st + (size_t)T * 64;       // T*64
    float* y_st  = es_st + (size_t)T * 64;       // T
    float* part  = y_st  + (size_t)T;            // T*7

    k_pre<<<T / 16, 256, 0, stream>>>(x, Wqy, Wenc, Wih, Aq, Ae, Ah);
    k_scan<<<1, 512, 0, stream>>>(Wqy, qpr, Wenc, Wem, Wes, Wih, Whh,
                                  yin, eu, ez, Aq, Ae, Ah,
                                  h_st, z_st, em_st, es_st, y_st);
    k_post<<<T, 256, 0, stream>>>(x, yin, Wpz, Wpzm, Wpzs, Wpy, ppr, Wqy, qpr,
                                  Wd, Wdm, Wds, Aq, h_st, z_st, em_st, es_st,
                                  y_st, part);
    k_final<<<7, 256, 0, stream>>>(part, (float*)d_out);
}

// Round 4
// 39584.830 us; speedup vs baseline: 2.5596x; 1.0060x over previous
//
#include <hip/hip_runtime.h>
#include <math.h>

#define T 16384

typedef float f32x4  __attribute__((ext_vector_type(4)));
typedef float f32x16 __attribute__((ext_vector_type(16)));

__device__ __forceinline__ float softplusf_(float x) {
    return (x > 15.f) ? x : __logf(1.f + __expf(x));
}
__device__ __forceinline__ float sigmoidf_(float x) {
    return 1.f / (1.f + __expf(-x));
}
__device__ __forceinline__ float tanh_fast(float x) {
    float xc = fminf(fmaxf(x, -15.f), 15.f);
    float e = __expf(2.f * xc);
    return (e - 1.f) / (e + 1.f);
}

// 16-wide dot-step, 4 accumulators, acc i takes lanes k%4==i (matches round-1
// summation order exactly — DO NOT REORDER: r2 showed reorder drift ~2%).
#define D16(A0,A1,A2,A3,HB,OFF,W) do{ \
  A0=fmaf((HB)[(OFF)+0],(W)[0],A0);  A1=fmaf((HB)[(OFF)+1],(W)[1],A1); \
  A2=fmaf((HB)[(OFF)+2],(W)[2],A2);  A3=fmaf((HB)[(OFF)+3],(W)[3],A3); \
  A0=fmaf((HB)[(OFF)+4],(W)[4],A0);  A1=fmaf((HB)[(OFF)+5],(W)[5],A1); \
  A2=fmaf((HB)[(OFF)+6],(W)[6],A2);  A3=fmaf((HB)[(OFF)+7],(W)[7],A3); \
  A0=fmaf((HB)[(OFF)+8],(W)[8],A0);  A1=fmaf((HB)[(OFF)+9],(W)[9],A1); \
  A2=fmaf((HB)[(OFF)+10],(W)[10],A2); A3=fmaf((HB)[(OFF)+11],(W)[11],A3); \
  A0=fmaf((HB)[(OFF)+12],(W)[12],A0); A1=fmaf((HB)[(OFF)+13],(W)[13],A1); \
  A2=fmaf((HB)[(OFF)+14],(W)[14],A2); A3=fmaf((HB)[(OFF)+15],(W)[15],A3); \
}while(0)

#define SET16(V,G,B) do{ \
  V[0]=G((B)+0);  V[1]=G((B)+1);  V[2]=G((B)+2);  V[3]=G((B)+3); \
  V[4]=G((B)+4);  V[5]=G((B)+5);  V[6]=G((B)+6);  V[7]=G((B)+7); \
  V[8]=G((B)+8);  V[9]=G((B)+9);  V[10]=G((B)+10); V[11]=G((B)+11); \
  V[12]=G((B)+12); V[13]=G((B)+13); V[14]=G((B)+14); V[15]=G((B)+15); \
}while(0)

// ---------------------------------------------------------------------------
// Precompute x-dependent matvec parts + logit(eps_u) (fully parallel).
// ---------------------------------------------------------------------------
__global__ __launch_bounds__(256) void k_pre(
    const float* __restrict__ x, const float* __restrict__ eu_g,
    const float* __restrict__ Wqy, const float* __restrict__ Wenc,
    const float* __restrict__ Wih,
    float* __restrict__ Aq, float* __restrict__ Ae, float* __restrict__ Ah,
    float* __restrict__ leu_g)
{
    __shared__ float xs[16 * 128];
    const int t0 = blockIdx.x * 16;
    for (int r = threadIdx.x; r < 16 * 128; r += 256) xs[r] = x[t0 * 128 + r];
    __syncthreads();
    const int j = threadIdx.x;
    if (j < 16) {
        float eu = eu_g[t0 + j];
        leu_g[t0 + j] = __logf(eu) - __logf(1.f - eu);
    }
    for (int tt = 0; tt < 16; ++tt) {
        float aq = 0.f, ae = 0.f;
#pragma unroll 8
        for (int i = 0; i < 128; ++i) {
            float xv = xs[tt * 128 + i];
            aq = fmaf(xv, Wqy[i * 256 + j], aq);
            ae = fmaf(xv, Wenc[i * 256 + j], ae);
        }
        Aq[(size_t)(t0 + tt) * 256 + j] = aq;
        Ae[(size_t)(t0 + tt) * 256 + j] = ae;
    }
    if (j < 128) {
        for (int tt = 0; tt < 16; ++tt) {
            float ah = 0.f;
#pragma unroll 8
            for (int i = 0; i < 128; ++i)
                ah = fmaf(xs[tt * 128 + i], Wih[(65 + i) * 128 + j], ah);
            Ah[(size_t)(t0 + tt) * 128 + j] = ah;
        }
    }
}

// ---------------------------------------------------------------------------
// Sequential scan. 1 block, 512 threads. waves_per_eu pinned to (2,2) so the
// allocator gets the full 256-VGPR budget -> 176 weight floats stay resident.
// ---------------------------------------------------------------------------
__global__ __launch_bounds__(512)
__attribute__((amdgpu_waves_per_eu(2, 2)))
void k_scan(
    const float* __restrict__ Wqy, const float* __restrict__ qpr,
    const float* __restrict__ Wenc,
    const float* __restrict__ Wem0, const float* __restrict__ Wes0,
    const float* __restrict__ Wih, const float* __restrict__ Whh,
    const float* __restrict__ yin_g, const float* __restrict__ leu_g,
    const float* __restrict__ ez_g,
    const float* __restrict__ Aq, const float* __restrict__ Ae,
    const float* __restrict__ Ah,
    float* __restrict__ h_st, float* __restrict__ z_st,
    float* __restrict__ em_st, float* __restrict__ es_st,
    float* __restrict__ y_st)
{
    const int tid = threadIdx.x;
    const int j   = tid >> 1, c1 = tid & 1;              // S1/S3 mapping
    const int m4  = tid >> 3; const int k4s = (tid >> 2) & 1; const int c4 = tid & 3; // S4
    const int o5  = tid >> 2, c5 = tid & 3;              // S5

    // ---- LDS (total ~153.5 KB of 160 KB) ----
    __shared__ __align__(16) f32x4 wq4[16][512];         // 128 KB: W_q_y h-part
    __shared__ __align__(16) float s_aq[4][256];
    __shared__ __align__(16) float s_ae[4][256];
    __shared__ __align__(16) float s_ah[4][128];
    __shared__ __align__(16) float s_ez[4][64];
    __shared__ __align__(16) float s_yin[4];
    __shared__ __align__(16) float s_leu[4];
    __shared__ __align__(16) float t_h[4][128];
    __shared__ __align__(16) float t_z[4][64];
    __shared__ __align__(16) float t_em[4][64];
    __shared__ __align__(16) float t_es[4][64];
    __shared__ float t_y[4];
    __shared__ __align__(16) float h_lds[2][128];
    __shared__ __align__(16) float h5c[2][4][132];       // padded replicas
    __shared__ __align__(16) float eh4[4][260];          // padded replicas
    __shared__ __align__(16) float z_lds[64];
    __shared__ float red[8];

    // ---- persistent weights in named vector registers (constant indices) ----
    f32x16 weh0, weh1, weh2, weh3, wms0, wms1, wms2, wms3, wh5a, wh5b, wz5v;
    {
        auto ge = [&](int k) { return Wenc[(129 + c1 * 64 + k) * 256 + j]; };
        SET16(weh0, ge, 0); SET16(weh1, ge, 16); SET16(weh2, ge, 32); SET16(weh3, ge, 48);
    }
    const float wey = Wenc[128 * 256 + j];
    const float qpj = qpr[j];
    {
        const float* Wm = k4s ? Wes0 : Wem0;
        auto gm = [&](int k) { return Wm[(c4 * 64 + k) * 64 + m4]; };
        SET16(wms0, gm, 0); SET16(wms1, gm, 16); SET16(wms2, gm, 32); SET16(wms3, gm, 48);
    }
    {
        auto gh = [&](int k) { return Whh[(c5 * 32 + k) * 128 + o5]; };
        SET16(wh5a, gh, 0); SET16(wh5b, gh, 16);
    }
    {
        auto gz = [&](int k) { return Wih[(1 + c5 * 16 + k) * 128 + o5]; };
        SET16(wz5v, gz, 0);
    }
    const float wihy = Wih[o5];

    // W_q_y h-part -> LDS, thread-major float4 (lane-consecutive => no conflicts)
    for (int kq = 0; kq < 16; ++kq) {
        f32x4 v;
        v[0] = Wqy[(128 + c1 * 64 + 4 * kq + 0) * 256 + j];
        v[1] = Wqy[(128 + c1 * 64 + 4 * kq + 1) * 256 + j];
        v[2] = Wqy[(128 + c1 * 64 + 4 * kq + 2) * 256 + j];
        v[3] = Wqy[(128 + c1 * 64 + 4 * kq + 3) * 256 + j];
        wq4[kq][tid] = v;
    }
    if (tid < 128) {
        h_lds[0][tid] = 0.f; h_lds[1][tid] = 0.f;
        h5c[0][0][tid] = 0.f; h5c[0][1][tid] = 0.f;
        h5c[0][2][tid] = 0.f; h5c[0][3][tid] = 0.f;
    }

    auto stage = [&](int t0) {
        if (tid < 256) {
            ((f32x4*)&s_aq[0][0])[tid] = ((const f32x4*)(Aq + (size_t)t0 * 256))[tid];
        } else {
            ((f32x4*)&s_ae[0][0])[tid - 256] = ((const f32x4*)(Ae + (size_t)t0 * 256))[tid - 256];
        }
        if (tid < 128) {
            ((f32x4*)&s_ah[0][0])[tid] = ((const f32x4*)(Ah + (size_t)t0 * 128))[tid];
        } else if (tid < 192) {
            ((f32x4*)&s_ez[0][0])[tid - 128] = ((const f32x4*)(ez_g + (size_t)t0 * 64))[tid - 128];
        } else if (tid == 192) {
            *(f32x4*)s_yin = *(const f32x4*)(yin_g + t0);
        } else if (tid == 193) {
            *(f32x4*)s_leu = *(const f32x4*)(leu_g + t0);
        }
    };
    auto flushb = [&](int t0) {
        if (tid < 128) {
            ((f32x4*)(h_st + (size_t)t0 * 128))[tid] = ((const f32x4*)&t_h[0][0])[tid];
        } else if (tid < 192) {
            ((f32x4*)(z_st + (size_t)t0 * 64))[tid - 128] = ((const f32x4*)&t_z[0][0])[tid - 128];
        } else if (tid < 256) {
            ((f32x4*)(em_st + (size_t)t0 * 64))[tid - 192] = ((const f32x4*)&t_em[0][0])[tid - 192];
        } else if (tid < 320) {
            ((f32x4*)(es_st + (size_t)t0 * 64))[tid - 256] = ((const f32x4*)&t_es[0][0])[tid - 256];
        } else if (tid < 324) {
            y_st[t0 + (tid - 320)] = t_y[tid - 320];
        }
    };

    for (int t0 = 0; t0 < T; t0 += 4) {
        if (t0) flushb(t0 - 4);
        stage(t0);
        __syncthreads();                                   // batch barrier

        for (int tt = 0; tt < 4; ++tt) {
            const int t = t0 + tt;
            const int cur = t & 1, nxt = cur ^ 1;
            const float aq  = s_aq[tt][j];
            const float ae  = s_ae[tt][j];
            const float yin = s_yin[tt];
            const float leu = s_leu[tt];
            const float ez  = s_ez[tt][m4];
            const float ah  = s_ah[tt][o5];
            const float* __restrict__ hb = &h_lds[cur][c1 * 64];

            float y_t;
            if (yin == -1.0f) {   // unlabeled (wave-uniform branch)
                float a0 = 0.f, a1 = 0.f, a2 = 0.f, a3 = 0.f;
#pragma unroll
                for (int kq = 0; kq < 16; ++kq) {
                    f32x4 w = wq4[kq][tid];
                    a0 = fmaf(hb[4 * kq + 0], w[0], a0);
                    a1 = fmaf(hb[4 * kq + 1], w[1], a1);
                    a2 = fmaf(hb[4 * kq + 2], w[2], a2);
                    a3 = fmaf(hb[4 * kq + 3], w[3], a3);
                }
                float s = (a0 + a1) + (a2 + a3);
                s += __shfl_xor(s, 1);
                float qh = fmaxf(aq + s, 0.f);
                float cq = (c1 == 0) ? qh * qpj : 0.f;
#pragma unroll
                for (int d = 1; d < 64; d <<= 1) cq += __shfl_xor(cq, d);
                if ((tid & 63) == 0) red[tid >> 6] = cq;
                __syncthreads();                           // B1
                float qlog = ((red[0] + red[1]) + (red[2] + red[3])) +
                             ((red[4] + red[5]) + (red[6] + red[7]));
                y_t = sigmoidf_(leu + qlog);
            } else {
                y_t = yin;
            }

            // S3: eh = relu(Ae + y*wey + h @ We_h)
            {
                float e0 = 0.f, e1 = 0.f, e2 = 0.f, e3 = 0.f;
                D16(e0, e1, e2, e3, hb, 0,  weh0);
                D16(e0, e1, e2, e3, hb, 16, weh1);
                D16(e0, e1, e2, e3, hb, 32, weh2);
                D16(e0, e1, e2, e3, hb, 48, weh3);
                float ehs = (e0 + e1) + (e2 + e3);
                ehs += __shfl_xor(ehs, 1);
                float eh = fmaxf(fmaf(y_t, wey, ae) + ehs, 0.f);
                if (c1 == 0) {
                    eh4[0][j] = eh; eh4[1][j] = eh; eh4[2][j] = eh; eh4[3][j] = eh;
                }
            }
            __syncthreads();                               // B3

            // S4: em/es = eh @ W_enc_mean/std ; z = ez*softplus(es)+em
            {
                const float* __restrict__ eb = &eh4[c4][c4 * 64];
                float b0 = 0.f, b1 = 0.f, b2 = 0.f, b3 = 0.f;
                D16(b0, b1, b2, b3, eb, 0,  wms0);
                D16(b0, b1, b2, b3, eb, 16, wms1);
                D16(b0, b1, b2, b3, eb, 32, wms2);
                D16(b0, b1, b2, b3, eb, 48, wms3);
                float s = (b0 + b1) + (b2 + b3);
                s += __shfl_xor(s, 1);
                s += __shfl_xor(s, 2);
                float other = __shfl_xor(s, 4);
                float em_pre = k4s ? other : s;
                float es_pre = k4s ? s : other;
                float es = softplusf_(es_pre);
                float zm = fmaf(ez, es, em_pre);
                if ((tid & 7) == 0) {
                    z_lds[m4] = zm;
                    t_z[tt][m4] = zm; t_em[tt][m4] = em_pre; t_es[tt][m4] = es;
                }
            }
            __syncthreads();                               // B4

            // S5: h_new = tanh(Ah + y*wihy + z @ Wih_z + h @ W_hh)
            {
                const float* __restrict__ zb  = &z_lds[c5 * 16];
                const float* __restrict__ hb5 = &h5c[cur][c5][c5 * 32];
                float g0 = 0.f, g1 = 0.f, g2 = 0.f, g3 = 0.f;
                D16(g0, g1, g2, g3, zb, 0, wz5v);
                D16(g0, g1, g2, g3, hb5, 0,  wh5a);
                D16(g0, g1, g2, g3, hb5, 16, wh5b);
                float s = (g0 + g1) + (g2 + g3);
                s += __shfl_xor(s, 1);
                s += __shfl_xor(s, 2);
                float hn = tanh_fast(fmaf(y_t, wihy, ah) + s);
                if (c5 == 0) {
                    h_lds[nxt][o5] = hn;
                    h5c[nxt][0][o5] = hn; h5c[nxt][1][o5] = hn;
                    h5c[nxt][2][o5] = hn; h5c[nxt][3][o5] = hn;
                    t_h[tt][o5] = hn;
                }
                if (tid == 0) t_y[tt] = y_t;
            }
            __syncthreads();                               // B5
        }
    }
    flushb(T - 4);
}

// ---------------------------------------------------------------------------
// Post-pass: one block per timestep (unchanged).
// ---------------------------------------------------------------------------
__global__ __launch_bounds__(256) void k_post(
    const float* __restrict__ x, const float* __restrict__ yin_g,
    const float* __restrict__ Wpz, const float* __restrict__ Wpzm,
    const float* __restrict__ Wpzs,
    const float* __restrict__ Wpy, const float* __restrict__ ppr,
    const float* __restrict__ Wqy, const float* __restrict__ qpr,
    const float* __restrict__ Wd, const float* __restrict__ Wdm,
    const float* __restrict__ Wds,
    const float* __restrict__ Aq,
    const float* __restrict__ h_st, const float* __restrict__ z_st,
    const float* __restrict__ em_st, const float* __restrict__ es_st,
    const float* __restrict__ y_st,
    float* __restrict__ part)
{
    const float CC = -0.9189385332046727f;  // -0.5*log(2*pi)
    const int t = blockIdx.x;
    const int tid = threadIdx.x;
    __shared__ float xp[128], xdv[128], xcv[128], hp[128];
    __shared__ float zp[64], ztv[64], emv[64], esv[64];
    __shared__ float pzh[256], dhv[256];
    __shared__ float pmv[64], psv[64], dmv[128], dsv[128];
    __shared__ float rl[16];

    const int tp = t ? (t - 1) : (T - 1);
    if (tid < 128) {
        xp[tid]  = x[(size_t)tp * 128 + tid];
        xdv[tid] = t ? x[(size_t)(t - 1) * 128 + tid] : 0.f;
        xcv[tid] = x[(size_t)t * 128 + tid];
        hp[tid]  = t ? h_st[(size_t)(t - 1) * 128 + tid] : 0.f;
    } else {
        int m = tid - 128;
        if (m < 64) {
            zp[m]  = t ? z_st[(size_t)(t - 1) * 64 + m] : 0.f;
            ztv[m] = z_st[(size_t)t * 64 + m];
        } else {
            m -= 64;
            emv[m] = em_st[(size_t)t * 64 + m];
            esv[m] = es_st[(size_t)t * 64 + m];
        }
    }
    __syncthreads();

    const float y_t = y_st[t];
    const float y_prev = t ? y_st[t - 1] : 0.f;
    const float lf = (yin_g[t] != -1.0f) ? 1.f : 0.f;
    const int jj = tid;

    float ap = 0.f;
#pragma unroll 4
    for (int i = 0; i < 128; ++i) ap = fmaf(xp[i], Wpy[i * 256 + jj], ap);
    ap = fmaf(y_prev, Wpy[128 * 256 + jj], ap);
    float cp = fmaxf(ap, 0.f) * ppr[jj];

    float aqv = Aq[(size_t)t * 256 + jj];
#pragma unroll 4
    for (int i = 0; i < 128; ++i) aqv = fmaf(hp[i], Wqy[(128 + i) * 256 + jj], aqv);
    float cq = fmaxf(aqv, 0.f) * qpr[jj];

    float az = 0.f;
#pragma unroll 4
    for (int m = 0; m < 64; ++m) az = fmaf(zp[m], Wpz[m * 256 + jj], az);
    pzh[jj] = fmaxf(az, 0.f);

    float ad = 0.f;
#pragma unroll 4
    for (int i = 0; i < 128; ++i) ad = fmaf(xdv[i], Wd[i * 256 + jj], ad);
#pragma unroll 4
    for (int m = 0; m < 64; ++m) ad = fmaf(ztv[m], Wd[(128 + m) * 256 + jj], ad);
    ad = fmaf(y_t, Wd[192 * 256 + jj], ad);
    dhv[jj] = fmaxf(ad, 0.f);
    __syncthreads();

    {
        const int i_ = tid & 127;
        const float* W = (tid < 128) ? Wdm : Wds;
        float a = 0.f;
#pragma unroll 4
        for (int q2 = 0; q2 < 256; ++q2) a = fmaf(dhv[q2], W[q2 * 128 + i_], a);
        if (tid < 128) dmv[i_] = a; else dsv[i_] = softplusf_(a);
    }
    if (tid < 128) {
        const int m = tid & 63;
        const float* W = (tid < 64) ? Wpzm : Wpzs;
        float a = 0.f;
#pragma unroll 4
        for (int q2 = 0; q2 < 256; ++q2) a = fmaf(pzh[q2], W[q2 * 64 + m], a);
        if (tid < 64) pmv[m] = a; else psv[m] = softplusf_(a);
    }
    __syncthreads();

    float kldc = 0.f, recc = 0.f;
    if (tid < 64) {
        float es = esv[tid], em = emv[tid], pm = pmv[tid], ps = psv[tid];
        float d = em - pm;
        kldc = __logf(ps / es) + (es * es + d * d) / (2.f * ps * ps) - 0.5f;
    }
    if (tid < 128) {
        float dm = dmv[tid], ds = dsv[tid], xv = xcv[tid];
        float d = xv - dm;
        recc = CC + __logf(ds) + d * d / (2.f * ds * ds);
    }

#pragma unroll
    for (int d = 1; d < 64; d <<= 1) {
        cp += __shfl_xor(cp, d);
        cq += __shfl_xor(cq, d);
        kldc += __shfl_xor(kldc, d);
        recc += __shfl_xor(recc, d);
    }
    if ((tid & 63) == 0) {
        const int w = tid >> 6;
        rl[w * 4 + 0] = cp; rl[w * 4 + 1] = cq;
        rl[w * 4 + 2] = kldc; rl[w * 4 + 3] = recc;
    }
    __syncthreads();
    if (tid == 0) {
        float plog = rl[0] + rl[4] + rl[8]  + rl[12];
        float qlog = rl[1] + rl[5] + rl[9]  + rl[13];
        float kld  = rl[2] + rl[6] + rl[10] + rl[14];
        float rec  = rl[3] + rl[7] + rl[11] + rl[15];
        float p = sigmoidf_(plog), q = sigmoidf_(qlog);
        float bce  = -(y_t * __logf(p) + (1.f - y_t) * __logf(1.f - p));
        float addt = y_t * __logf(p * q) + (1.f - y_t) * __logf((1.f - p) * (1.f - q));
        float kcat = p * __logf(p / q) + (1.f - p) * __logf((1.f - p) / (1.f - q));
        float ul = 1.f - lf;
        float* pr = part + (size_t)t * 7;
        pr[0] = lf * kld;  pr[1] = lf * rec;  pr[2] = lf * bce;
        pr[3] = ul * kld;  pr[4] = ul * rec;  pr[5] = ul * kcat;
        pr[6] = lf * addt;
    }
}

__global__ __launch_bounds__(256) void k_final(const float* __restrict__ part,
                                               float* __restrict__ out)
{
    const int o = blockIdx.x;
    float s = 0.f;
    for (int b = threadIdx.x; b < T; b += 256) s += part[(size_t)b * 7 + o];
#pragma unroll
    for (int d = 1; d < 64; d <<= 1) s += __shfl_xor(s, d);
    __shared__ float l[4];
    if ((threadIdx.x & 63) == 0) l[threadIdx.x >> 6] = s;
    __syncthreads();
    if (threadIdx.x == 0) out[o] = (l[0] + l[1]) + (l[2] + l[3]);
}

extern "C" void kernel_launch(void* const* d_in, const int* in_sizes, int n_in,
                              void* d_out, int out_size, void* d_ws, size_t ws_size,
                              hipStream_t stream) {
    (void)in_sizes; (void)n_in; (void)out_size; (void)ws_size;
    const float* x    = (const float*)d_in[0];
    const float* yin  = (const float*)d_in[1];
    const float* ez   = (const float*)d_in[2];
    const float* eu   = (const float*)d_in[3];
    const float* Wpz  = (const float*)d_in[4];
    const float* Wpzm = (const float*)d_in[5];
    const float* Wpzs = (const float*)d_in[6];
    const float* Wpy  = (const float*)d_in[7];
    const float* ppr  = (const float*)d_in[8];
    const float* Wqy  = (const float*)d_in[9];
    const float* qpr  = (const float*)d_in[10];
    const float* Wenc = (const float*)d_in[11];
    const float* Wem  = (const float*)d_in[12];
    const float* Wes  = (const float*)d_in[13];
    const float* Wd   = (const float*)d_in[14];
    const float* Wdm  = (const float*)d_in[15];
    const float* Wds  = (const float*)d_in[16];
    const float* Wih  = (const float*)d_in[17];
    const float* Whh  = (const float*)d_in[18];

    float* ws = (float*)d_ws;
    float* Aq    = ws;                           // T*256
    float* Ae    = Aq    + (size_t)T * 256;      // T*256
    float* Ah    = Ae    + (size_t)T * 256;      // T*128
    float* h_st  = Ah    + (size_t)T * 128;      // T*128
    float* z_st  = h_st  + (size_t)T * 128;      // T*64
    float* em_st = z_st  + (size_t)T * 64;       // T*64
    float* es_st = em_st + (size_t)T * 64;       // T*64
    float* y_st  = es_st + (size_t)T * 64;       // T
    float* part  = y_st  + (size_t)T;            // T*7
    float* leu   = part  + (size_t)T * 7;        // T

    k_pre<<<T / 16, 256, 0, stream>>>(x, eu, Wqy, Wenc, Wih, Aq, Ae, Ah, leu);
    k_scan<<<1, 512, 0, stream>>>(Wqy, qpr, Wenc, Wem, Wes, Wih, Whh,
                                  yin, leu, ez, Aq, Ae, Ah,
                                  h_st, z_st, em_st, es_st, y_st);
    k_post<<<T, 256, 0, stream>>>(x, yin, Wpz, Wpzm, Wpzs, Wpy, ppr, Wqy, qpr,
                                  Wd, Wdm, Wds, Aq, h_st, z_st, em_st, es_st,
                                  y_st, part);
    k_final<<<7, 256, 0, stream>>>(part, (float*)d_out);
}

// Round 5
// 39380.249 us; speedup vs baseline: 2.5729x; 1.0052x over previous
//
#include <hip/hip_runtime.h>
#include <math.h>

#define T 16384

typedef float f32x4  __attribute__((ext_vector_type(4)));
typedef float f32x16 __attribute__((ext_vector_type(16)));

__device__ __forceinline__ float softplusf_(float x) {
    return (x > 15.f) ? x : __logf(1.f + __expf(x));
}
__device__ __forceinline__ float sigmoidf_(float x) {
    return 1.f / (1.f + __expf(-x));
}
__device__ __forceinline__ float tanh_fast(float x) {
    float xc = fminf(fmaxf(x, -15.f), 15.f);
    float e = __expf(2.f * xc);
    return (e - 1.f) / (e + 1.f);
}

// 16-wide dot-step, 4 accumulators, acc i takes lanes k%4==i (matches round-1
// summation order exactly — DO NOT REORDER: r2 showed reorder drift ~2%).
#define D16(A0,A1,A2,A3,HB,OFF,W) do{ \
  A0=fmaf((HB)[(OFF)+0],(W)[0],A0);  A1=fmaf((HB)[(OFF)+1],(W)[1],A1); \
  A2=fmaf((HB)[(OFF)+2],(W)[2],A2);  A3=fmaf((HB)[(OFF)+3],(W)[3],A3); \
  A0=fmaf((HB)[(OFF)+4],(W)[4],A0);  A1=fmaf((HB)[(OFF)+5],(W)[5],A1); \
  A2=fmaf((HB)[(OFF)+6],(W)[6],A2);  A3=fmaf((HB)[(OFF)+7],(W)[7],A3); \
  A0=fmaf((HB)[(OFF)+8],(W)[8],A0);  A1=fmaf((HB)[(OFF)+9],(W)[9],A1); \
  A2=fmaf((HB)[(OFF)+10],(W)[10],A2); A3=fmaf((HB)[(OFF)+11],(W)[11],A3); \
  A0=fmaf((HB)[(OFF)+12],(W)[12],A0); A1=fmaf((HB)[(OFF)+13],(W)[13],A1); \
  A2=fmaf((HB)[(OFF)+14],(W)[14],A2); A3=fmaf((HB)[(OFF)+15],(W)[15],A3); \
}while(0)

#define SET16(V,G,B) do{ \
  V[0]=G((B)+0);  V[1]=G((B)+1);  V[2]=G((B)+2);  V[3]=G((B)+3); \
  V[4]=G((B)+4);  V[5]=G((B)+5);  V[6]=G((B)+6);  V[7]=G((B)+7); \
  V[8]=G((B)+8);  V[9]=G((B)+9);  V[10]=G((B)+10); V[11]=G((B)+11); \
  V[12]=G((B)+12); V[13]=G((B)+13); V[14]=G((B)+14); V[15]=G((B)+15); \
}while(0)

// ---------------------------------------------------------------------------
// Precompute x-dependent matvec parts + logit(eps_u) (fully parallel).
// ---------------------------------------------------------------------------
__global__ __launch_bounds__(256) void k_pre(
    const float* __restrict__ x, const float* __restrict__ eu_g,
    const float* __restrict__ Wqy, const float* __restrict__ Wenc,
    const float* __restrict__ Wih,
    float* __restrict__ Aq, float* __restrict__ Ae, float* __restrict__ Ah,
    float* __restrict__ leu_g)
{
    __shared__ float xs[16 * 128];
    const int t0 = blockIdx.x * 16;
    for (int r = threadIdx.x; r < 16 * 128; r += 256) xs[r] = x[t0 * 128 + r];
    __syncthreads();
    const int j = threadIdx.x;
    if (j < 16) {
        float eu = eu_g[t0 + j];
        leu_g[t0 + j] = __logf(eu) - __logf(1.f - eu);
    }
    for (int tt = 0; tt < 16; ++tt) {
        float aq = 0.f, ae = 0.f;
#pragma unroll 8
        for (int i = 0; i < 128; ++i) {
            float xv = xs[tt * 128 + i];
            aq = fmaf(xv, Wqy[i * 256 + j], aq);
            ae = fmaf(xv, Wenc[i * 256 + j], ae);
        }
        Aq[(size_t)(t0 + tt) * 256 + j] = aq;
        Ae[(size_t)(t0 + tt) * 256 + j] = ae;
    }
    if (j < 128) {
        for (int tt = 0; tt < 16; ++tt) {
            float ah = 0.f;
#pragma unroll 8
            for (int i = 0; i < 128; ++i)
                ah = fmaf(xs[tt * 128 + i], Wih[(65 + i) * 128 + j], ah);
            Ah[(size_t)(t0 + tt) * 128 + j] = ah;
        }
    }
}

// ---------------------------------------------------------------------------
// Sequential scan. 1 block, 512 threads. Weights loaded via VOLATILE pointers
// (kills rematerialization: load-once semantics) + waves_per_eu(2,2) gives
// the allocator a 256-VGPR budget to keep them resident.
// ---------------------------------------------------------------------------
__global__
__attribute__((amdgpu_flat_work_group_size(512, 512)))
__attribute__((amdgpu_waves_per_eu(2, 2)))
void k_scan(
    const float* __restrict__ Wqy, const float* __restrict__ qpr,
    const float* __restrict__ Wenc,
    const float* __restrict__ Wem0, const float* __restrict__ Wes0,
    const float* __restrict__ Wih, const float* __restrict__ Whh,
    const float* __restrict__ yin_g, const float* __restrict__ leu_g,
    const float* __restrict__ ez_g,
    const float* __restrict__ Aq, const float* __restrict__ Ae,
    const float* __restrict__ Ah,
    float* __restrict__ h_st, float* __restrict__ z_st,
    float* __restrict__ em_st, float* __restrict__ es_st,
    float* __restrict__ y_st)
{
    const int tid = threadIdx.x;
    const int j   = tid >> 1, c1 = tid & 1;              // S1/S3 mapping
    const int m4  = tid >> 3; const int k4s = (tid >> 2) & 1; const int c4 = tid & 3; // S4
    const int o5  = tid >> 2, c5 = tid & 3;              // S5

    // ---- LDS (total ~153.5 KB of 160 KB) ----
    __shared__ __align__(16) f32x4 wq4[16][512];         // 128 KB: W_q_y h-part
    __shared__ __align__(16) float s_aq[4][256];
    __shared__ __align__(16) float s_ae[4][256];
    __shared__ __align__(16) float s_ah[4][128];
    __shared__ __align__(16) float s_ez[4][64];
    __shared__ __align__(16) float s_yin[4];
    __shared__ __align__(16) float s_leu[4];
    __shared__ __align__(16) float t_h[4][128];
    __shared__ __align__(16) float t_z[4][64];
    __shared__ __align__(16) float t_em[4][64];
    __shared__ __align__(16) float t_es[4][64];
    __shared__ float t_y[4];
    __shared__ __align__(16) float h_lds[2][128];
    __shared__ __align__(16) float h5c[2][4][132];       // padded replicas
    __shared__ __align__(16) float eh4[4][260];          // padded replicas
    __shared__ __align__(16) float z_lds[64];
    __shared__ float red[8];

    // ---- persistent weights: VOLATILE loads (load-once, no remat) ----
    f32x16 weh0, weh1, weh2, weh3, wms0, wms1, wms2, wms3, wh5a, wh5b, wz5v;
    {
        volatile const float* W = Wenc;
        auto ge = [&](int k) { return W[(129 + c1 * 64 + k) * 256 + j]; };
        SET16(weh0, ge, 0); SET16(weh1, ge, 16); SET16(weh2, ge, 32); SET16(weh3, ge, 48);
    }
    const float wey = Wenc[128 * 256 + j];
    const float qpj = qpr[j];
    {
        volatile const float* Wm = k4s ? Wes0 : Wem0;
        auto gm = [&](int k) { return Wm[(c4 * 64 + k) * 64 + m4]; };
        SET16(wms0, gm, 0); SET16(wms1, gm, 16); SET16(wms2, gm, 32); SET16(wms3, gm, 48);
    }
    {
        volatile const float* W = Whh;
        auto gh = [&](int k) { return W[(c5 * 32 + k) * 128 + o5]; };
        SET16(wh5a, gh, 0); SET16(wh5b, gh, 16);
    }
    {
        volatile const float* W = Wih;
        auto gz = [&](int k) { return W[(1 + c5 * 16 + k) * 128 + o5]; };
        SET16(wz5v, gz, 0);
    }
    const float wihy = Wih[o5];

    // W_q_y h-part -> LDS, thread-major float4 (lane-consecutive => no conflicts)
    for (int kq = 0; kq < 16; ++kq) {
        f32x4 v;
        v[0] = Wqy[(128 + c1 * 64 + 4 * kq + 0) * 256 + j];
        v[1] = Wqy[(128 + c1 * 64 + 4 * kq + 1) * 256 + j];
        v[2] = Wqy[(128 + c1 * 64 + 4 * kq + 2) * 256 + j];
        v[3] = Wqy[(128 + c1 * 64 + 4 * kq + 3) * 256 + j];
        wq4[kq][tid] = v;
    }
    if (tid < 128) {
        h_lds[0][tid] = 0.f; h_lds[1][tid] = 0.f;
        h5c[0][0][tid] = 0.f; h5c[0][1][tid] = 0.f;
        h5c[0][2][tid] = 0.f; h5c[0][3][tid] = 0.f;
    }

    // ---- async batch staging: global -> regs (early) -> LDS (late) ----
    f32x4 pA, pC;
    auto load_regs = [&](int t0) {
        if (tid < 256) pA = ((const f32x4*)(Aq + (size_t)t0 * 256))[tid];
        else           pA = ((const f32x4*)(Ae + (size_t)t0 * 256))[tid - 256];
        if (tid < 128)       pC = ((const f32x4*)(Ah + (size_t)t0 * 128))[tid];
        else if (tid < 192)  pC = ((const f32x4*)(ez_g + (size_t)t0 * 64))[tid - 128];
        else if (tid == 192) pC = *(const f32x4*)(yin_g + t0);
        else if (tid == 193) pC = *(const f32x4*)(leu_g + t0);
    };
    auto write_regs = [&]() {
        if (tid < 256) ((f32x4*)&s_aq[0][0])[tid] = pA;
        else           ((f32x4*)&s_ae[0][0])[tid - 256] = pA;
        if (tid < 128)       ((f32x4*)&s_ah[0][0])[tid] = pC;
        else if (tid < 192)  ((f32x4*)&s_ez[0][0])[tid - 128] = pC;
        else if (tid == 192) *(f32x4*)s_yin = pC;
        else if (tid == 193) *(f32x4*)s_leu = pC;
    };
    auto flushb = [&](int t0) {
        if (tid < 128) {
            ((f32x4*)(h_st + (size_t)t0 * 128))[tid] = ((const f32x4*)&t_h[0][0])[tid];
        } else if (tid < 192) {
            ((f32x4*)(z_st + (size_t)t0 * 64))[tid - 128] = ((const f32x4*)&t_z[0][0])[tid - 128];
        } else if (tid < 256) {
            ((f32x4*)(em_st + (size_t)t0 * 64))[tid - 192] = ((const f32x4*)&t_em[0][0])[tid - 192];
        } else if (tid < 320) {
            ((f32x4*)(es_st + (size_t)t0 * 64))[tid - 256] = ((const f32x4*)&t_es[0][0])[tid - 256];
        } else if (tid < 324) {
            y_st[t0 + (tid - 320)] = t_y[tid - 320];
        }
    };

    // prologue: stage batch 0
    load_regs(0);
    write_regs();
    __syncthreads();

    for (int t0 = 0; t0 < T; t0 += 4) {
        const int tnb = (t0 + 4 < T) ? t0 + 4 : t0;
        load_regs(tnb);                                    // issue early (T14)

        for (int tt = 0; tt < 4; ++tt) {
            const int t = t0 + tt;
            const int cur = t & 1, nxt = cur ^ 1;
            const float aq  = s_aq[tt][j];
            const float ae  = s_ae[tt][j];
            const float yin = s_yin[tt];
            const float leu = s_leu[tt];
            const float ez  = s_ez[tt][m4];
            const float ah  = s_ah[tt][o5];
            const float* __restrict__ hb = &h_lds[cur][c1 * 64];

            float y_t;
            if (yin == -1.0f) {   // unlabeled (block-uniform branch)
                float a0 = 0.f, a1 = 0.f, a2 = 0.f, a3 = 0.f;
#pragma unroll
                for (int kq = 0; kq < 16; ++kq) {
                    f32x4 w = wq4[kq][tid];
                    a0 = fmaf(hb[4 * kq + 0], w[0], a0);
                    a1 = fmaf(hb[4 * kq + 1], w[1], a1);
                    a2 = fmaf(hb[4 * kq + 2], w[2], a2);
                    a3 = fmaf(hb[4 * kq + 3], w[3], a3);
                }
                float s = (a0 + a1) + (a2 + a3);
                s += __shfl_xor(s, 1);
                float qh = fmaxf(aq + s, 0.f);
                float cq = (c1 == 0) ? qh * qpj : 0.f;
#pragma unroll
                for (int d = 1; d < 64; d <<= 1) cq += __shfl_xor(cq, d);
                if ((tid & 63) == 0) red[tid >> 6] = cq;
                __syncthreads();                           // B1
                float qlog = ((red[0] + red[1]) + (red[2] + red[3])) +
                             ((red[4] + red[5]) + (red[6] + red[7]));
                y_t = sigmoidf_(leu + qlog);
            } else {
                y_t = yin;
            }

            // S3: eh = relu(Ae + y*wey + h @ We_h)
            {
                float e0 = 0.f, e1 = 0.f, e2 = 0.f, e3 = 0.f;
                D16(e0, e1, e2, e3, hb, 0,  weh0);
                D16(e0, e1, e2, e3, hb, 16, weh1);
                D16(e0, e1, e2, e3, hb, 32, weh2);
                D16(e0, e1, e2, e3, hb, 48, weh3);
                float ehs = (e0 + e1) + (e2 + e3);
                ehs += __shfl_xor(ehs, 1);
                float eh = fmaxf(fmaf(y_t, wey, ae) + ehs, 0.f);
                if (c1 == 0) {
                    eh4[0][j] = eh; eh4[1][j] = eh; eh4[2][j] = eh; eh4[3][j] = eh;
                }
            }
            __syncthreads();                               // B3

            // S4: em/es = eh @ W_enc_mean/std ; z = ez*softplus(es)+em
            {
                const float* __restrict__ eb = &eh4[c4][c4 * 64];
                float b0 = 0.f, b1 = 0.f, b2 = 0.f, b3 = 0.f;
                D16(b0, b1, b2, b3, eb, 0,  wms0);
                D16(b0, b1, b2, b3, eb, 16, wms1);
                D16(b0, b1, b2, b3, eb, 32, wms2);
                D16(b0, b1, b2, b3, eb, 48, wms3);
                float s = (b0 + b1) + (b2 + b3);
                s += __shfl_xor(s, 1);
                s += __shfl_xor(s, 2);
                float other = __shfl_xor(s, 4);
                float em_pre = k4s ? other : s;
                float es_pre = k4s ? s : other;
                float es = softplusf_(es_pre);
                float zm = fmaf(ez, es, em_pre);
                if ((tid & 7) == 0) {
                    z_lds[m4] = zm;
                    t_z[tt][m4] = zm; t_em[tt][m4] = em_pre; t_es[tt][m4] = es;
                }
            }
            __syncthreads();                               // B4

            // S5: h_new = tanh(Ah + y*wihy + z @ Wih_z + h @ W_hh)
            {
                const float* __restrict__ zb  = &z_lds[c5 * 16];
                const float* __restrict__ hb5 = &h5c[cur][c5][c5 * 32];
                float g0 = 0.f, g1 = 0.f, g2 = 0.f, g3 = 0.f;
                D16(g0, g1, g2, g3, zb, 0, wz5v);
                D16(g0, g1, g2, g3, hb5, 0,  wh5a);
                D16(g0, g1, g2, g3, hb5, 16, wh5b);
                float s = (g0 + g1) + (g2 + g3);
                s += __shfl_xor(s, 1);
                s += __shfl_xor(s, 2);
                float hn = tanh_fast(fmaf(y_t, wihy, ah) + s);
                if (c5 == 0) {
                    h_lds[nxt][o5] = hn;
                    h5c[nxt][0][o5] = hn; h5c[nxt][1][o5] = hn;
                    h5c[nxt][2][o5] = hn; h5c[nxt][3][o5] = hn;
                    t_h[tt][o5] = hn;
                }
                if (tid == 0) t_y[tt] = y_t;
            }
            __syncthreads();                               // B5
        }

        flushb(t0);            // trajectory for this batch (t_* complete)
        write_regs();          // s_* for next batch (loads long in flight)
        __syncthreads();       // batch barrier
    }
}

// ---------------------------------------------------------------------------
// Post-pass: one block per timestep (unchanged).
// ---------------------------------------------------------------------------
__global__ __launch_bounds__(256) void k_post(
    const float* __restrict__ x, const float* __restrict__ yin_g,
    const float* __restrict__ Wpz, const float* __restrict__ Wpzm,
    const float* __restrict__ Wpzs,
    const float* __restrict__ Wpy, const float* __restrict__ ppr,
    const float* __restrict__ Wqy, const float* __restrict__ qpr,
    const float* __restrict__ Wd, const float* __restrict__ Wdm,
    const float* __restrict__ Wds,
    const float* __restrict__ Aq,
    const float* __restrict__ h_st, const float* __restrict__ z_st,
    const float* __restrict__ em_st, const float* __restrict__ es_st,
    const float* __restrict__ y_st,
    float* __restrict__ part)
{
    const float CC = -0.9189385332046727f;  // -0.5*log(2*pi)
    const int t = blockIdx.x;
    const int tid = threadIdx.x;
    __shared__ float xp[128], xdv[128], xcv[128], hp[128];
    __shared__ float zp[64], ztv[64], emv[64], esv[64];
    __shared__ float pzh[256], dhv[256];
    __shared__ float pmv[64], psv[64], dmv[128], dsv[128];
    __shared__ float rl[16];

    const int tp = t ? (t - 1) : (T - 1);
    if (tid < 128) {
        xp[tid]  = x[(size_t)tp * 128 + tid];
        xdv[tid] = t ? x[(size_t)(t - 1) * 128 + tid] : 0.f;
        xcv[tid] = x[(size_t)t * 128 + tid];
        hp[tid]  = t ? h_st[(size_t)(t - 1) * 128 + tid] : 0.f;
    } else {
        int m = tid - 128;
        if (m < 64) {
            zp[m]  = t ? z_st[(size_t)(t - 1) * 64 + m] : 0.f;
            ztv[m] = z_st[(size_t)t * 64 + m];
        } else {
            m -= 64;
            emv[m] = em_st[(size_t)t * 64 + m];
            esv[m] = es_st[(size_t)t * 64 + m];
        }
    }
    __syncthreads();

    const float y_t = y_st[t];
    const float y_prev = t ? y_st[t - 1] : 0.f;
    const float lf = (yin_g[t] != -1.0f) ? 1.f : 0.f;
    const int jj = tid;

    float ap = 0.f;
#pragma unroll 4
    for (int i = 0; i < 128; ++i) ap = fmaf(xp[i], Wpy[i * 256 + jj], ap);
    ap = fmaf(y_prev, Wpy[128 * 256 + jj], ap);
    float cp = fmaxf(ap, 0.f) * ppr[jj];

    float aqv = Aq[(size_t)t * 256 + jj];
#pragma unroll 4
    for (int i = 0; i < 128; ++i) aqv = fmaf(hp[i], Wqy[(128 + i) * 256 + jj], aqv);
    float cq = fmaxf(aqv, 0.f) * qpr[jj];

    float az = 0.f;
#pragma unroll 4
    for (int m = 0; m < 64; ++m) az = fmaf(zp[m], Wpz[m * 256 + jj], az);
    pzh[jj] = fmaxf(az, 0.f);

    float ad = 0.f;
#pragma unroll 4
    for (int i = 0; i < 128; ++i) ad = fmaf(xdv[i], Wd[i * 256 + jj], ad);
#pragma unroll 4
    for (int m = 0; m < 64; ++m) ad = fmaf(ztv[m], Wd[(128 + m) * 256 + jj], ad);
    ad = fmaf(y_t, Wd[192 * 256 + jj], ad);
    dhv[jj] = fmaxf(ad, 0.f);
    __syncthreads();

    {
        const int i_ = tid & 127;
        const float* W = (tid < 128) ? Wdm : Wds;
        float a = 0.f;
#pragma unroll 4
        for (int q2 = 0; q2 < 256; ++q2) a = fmaf(dhv[q2], W[q2 * 128 + i_], a);
        if (tid < 128) dmv[i_] = a; else dsv[i_] = softplusf_(a);
    }
    if (tid < 128) {
        const int m = tid & 63;
        const float* W = (tid < 64) ? Wpzm : Wpzs;
        float a = 0.f;
#pragma unroll 4
        for (int q2 = 0; q2 < 256; ++q2) a = fmaf(pzh[q2], W[q2 * 64 + m], a);
        if (tid < 64) pmv[m] = a; else psv[m] = softplusf_(a);
    }
    __syncthreads();

    float kldc = 0.f, recc = 0.f;
    if (tid < 64) {
        float es = esv[tid], em = emv[tid], pm = pmv[tid], ps = psv[tid];
        float d = em - pm;
        kldc = __logf(ps / es) + (es * es + d * d) / (2.f * ps * ps) - 0.5f;
    }
    if (tid < 128) {
        float dm = dmv[tid], ds = dsv[tid], xv = xcv[tid];
        float d = xv - dm;
        recc = CC + __logf(ds) + d * d / (2.f * ds * ds);
    }

#pragma unroll
    for (int d = 1; d < 64; d <<= 1) {
        cp += __shfl_xor(cp, d);
        cq += __shfl_xor(cq, d);
        kldc += __shfl_xor(kldc, d);
        recc += __shfl_xor(recc, d);
    }
    if ((tid & 63) == 0) {
        const int w = tid >> 6;
        rl[w * 4 + 0] = cp; rl[w * 4 + 1] = cq;
        rl[w * 4 + 2] = kldc; rl[w * 4 + 3] = recc;
    }
    __syncthreads();
    if (tid == 0) {
        float plog = rl[0] + rl[4] + rl[8]  + rl[12];
        float qlog = rl[1] + rl[5] + rl[9]  + rl[13];
        float kld  = rl[2] + rl[6] + rl[10] + rl[14];
        float rec  = rl[3] + rl[7] + rl[11] + rl[15];
        float p = sigmoidf_(plog), q = sigmoidf_(qlog);
        float bce  = -(y_t * __logf(p) + (1.f - y_t) * __logf(1.f - p));
        float addt = y_t * __logf(p * q) + (1.f - y_t) * __logf((1.f - p) * (1.f - q));
        float kcat = p * __logf(p / q) + (1.f - p) * __logf((1.f - p) / (1.f - q));
        float ul = 1.f - lf;
        float* pr = part + (size_t)t * 7;
        pr[0] = lf * kld;  pr[1] = lf * rec;  pr[2] = lf * bce;
        pr[3] = ul * kld;  pr[4] = ul * rec;  pr[5] = ul * kcat;
        pr[6] = lf * addt;
    }
}

__global__ __launch_bounds__(256) void k_final(const float* __restrict__ part,
                                               float* __restrict__ out)
{
    const int o = blockIdx.x;
    float s = 0.f;
    for (int b = threadIdx.x; b < T; b += 256) s += part[(size_t)b * 7 + o];
#pragma unroll
    for (int d = 1; d < 64; d <<= 1) s += __shfl_xor(s, d);
    __shared__ float l[4];
    if ((threadIdx.x & 63) == 0) l[threadIdx.x >> 6] = s;
    __syncthreads();
    if (threadIdx.x == 0) out[o] = (l[0] + l[1]) + (l[2] + l[3]);
}

extern "C" void kernel_launch(void* const* d_in, const int* in_sizes, int n_in,
                              void* d_out, int out_size, void* d_ws, size_t ws_size,
                              hipStream_t stream) {
    (void)in_sizes; (void)n_in; (void)out_size; (void)ws_size;
    const float* x    = (const float*)d_in[0];
    const float* yin  = (const float*)d_in[1];
    const float* ez   = (const float*)d_in[2];
    const float* eu   = (const float*)d_in[3];
    const float* Wpz  = (const float*)d_in[4];
    const float* Wpzm = (const float*)d_in[5];
    const float* Wpzs = (const float*)d_in[6];
    const float* Wpy  = (const float*)d_in[7];
    const float* ppr  = (const float*)d_in[8];
    const float* Wqy  = (const float*)d_in[9];
    const float* qpr  = (const float*)d_in[10];
    const float* Wenc = (const float*)d_in[11];
    const float* Wem  = (const float*)d_in[12];
    const float* Wes  = (const float*)d_in[13];
    const float* Wd   = (const float*)d_in[14];
    const float* Wdm  = (const float*)d_in[15];
    const float* Wds  = (const float*)d_in[16];
    const float* Wih  = (const float*)d_in[17];
    const float* Whh  = (const float*)d_in[18];

    float* ws = (float*)d_ws;
    float* Aq    = ws;                           // T*256
    float* Ae    = Aq    + (size_t)T * 256;      // T*256
    float* Ah    = Ae    + (size_t)T * 256;      // T*128
    float* h_st  = Ah    + (size_t)T * 128;      // T*128
    float* z_st  = h_st  + (size_t)T * 128;      // T*64
    float* em_st = z_st  + (size_t)T * 64;       // T*64
    float* es_st = em_st + (size_t)T * 64;       // T*64
    float* y_st  = es_st + (size_t)T * 64;       // T
    float* part  = y_st  + (size_t)T;            // T*7
    float* leu   = part  + (size_t)T * 7;        // T

    k_pre<<<T / 16, 256, 0, stream>>>(x, eu, Wqy, Wenc, Wih, Aq, Ae, Ah, leu);
    k_scan<<<1, 512, 0, stream>>>(Wqy, qpr, Wenc, Wem, Wes, Wih, Whh,
                                  yin, leu, ez, Aq, Ae, Ah,
                                  h_st, z_st, em_st, es_st, y_st);
    k_post<<<T, 256, 0, stream>>>(x, yin, Wpz, Wpzm, Wpzs, Wpy, ppr, Wqy, qpr,
                                  Wd, Wdm, Wds, Aq, h_st, z_st, em_st, es_st,
                                  y_st, part);
    k_final<<<7, 256, 0, stream>>>(part, (float*)d_out);
}